// Round 1
// baseline (401.812 us; speedup 1.0000x reference)
//
#include <hip/hip_runtime.h>
#include <math.h>

// ---------------------------------------------------------------------------
// LinearBlock: LN -> QKV -> causal linear attention (elu+1) -> Wo+res -> LN
//              -> GELU MLP + res.   B=2 T=1024 D=1024 H=16 DH=64 FF=4096
// Strategy: bf16 MFMA for all GEMMs (fp32 accum), fp32 chunked linear attn.
// ---------------------------------------------------------------------------

typedef __attribute__((ext_vector_type(8))) __bf16 bf16x8;
typedef __attribute__((ext_vector_type(8))) unsigned short us8;
typedef __attribute__((ext_vector_type(4))) float f32x4;

__device__ __forceinline__ unsigned short f2bf(float f) {
  unsigned int u = __builtin_bit_cast(unsigned int, f);
  unsigned int r = (u + 0x7fffu + ((u >> 16) & 1u)) >> 16;  // RNE
  return (unsigned short)r;
}
__device__ __forceinline__ float phi_fn(float x) {  // elu(x)+1
  return x > 0.f ? x + 1.f : __expf(x);
}

// ---------------- weight convert + transpose: fp32 [K][N] -> bf16 [N][K] ----
__global__ __launch_bounds__(256) void cvt_transpose(
    const float* __restrict__ W, unsigned short* __restrict__ WT, int K, int N)
{
  __shared__ unsigned short tile[64][72];
  const int n0 = blockIdx.x * 64, k0 = blockIdx.y * 64;
  const int tid = threadIdx.x;
  for (int it = 0; it < 16; ++it) {
    const int lin = it * 256 + tid;
    const int i = lin >> 6, j = lin & 63;            // i: k, j: n
    tile[j][i] = f2bf(W[(size_t)(k0 + i) * N + n0 + j]);
  }
  __syncthreads();
  for (int it = 0; it < 16; ++it) {
    const int lin = it * 256 + tid;
    const int j = lin >> 6, i = lin & 63;
    WT[(size_t)(n0 + j) * K + k0 + i] = tile[j][i];
  }
}

// ---------------- LayerNorm (D=1024) fp32 in -> bf16 out --------------------
__global__ __launch_bounds__(256) void ln_to_bf16(
    const float* __restrict__ x, const float* __restrict__ g,
    const float* __restrict__ b, unsigned short* __restrict__ out)
{
  const int row = blockIdx.x;
  const int tid = threadIdx.x;
  const float4 xv = *(const float4*)&x[(size_t)row * 1024 + tid * 4];
  float xa[4] = {xv.x, xv.y, xv.z, xv.w};
  float s = xa[0] + xa[1] + xa[2] + xa[3];
  float sq = xa[0]*xa[0] + xa[1]*xa[1] + xa[2]*xa[2] + xa[3]*xa[3];
  for (int off = 32; off > 0; off >>= 1) {
    s += __shfl_down(s, off);
    sq += __shfl_down(sq, off);
  }
  __shared__ float red[8];
  if ((tid & 63) == 0) { red[tid >> 6] = s; red[4 + (tid >> 6)] = sq; }
  __syncthreads();
  const float ts = red[0] + red[1] + red[2] + red[3];
  const float tq = red[4] + red[5] + red[6] + red[7];
  const float mean = ts * (1.f / 1024.f);
  const float var = tq * (1.f / 1024.f) - mean * mean;
  const float inv = rsqrtf(var + 1e-5f);
  unsigned short o[4];
#pragma unroll
  for (int j = 0; j < 4; ++j) {
    const int col = tid * 4 + j;
    o[j] = f2bf((xa[j] - mean) * inv * g[col] + b[col]);
  }
  unsigned int p0 = (unsigned)o[0] | ((unsigned)o[1] << 16);
  unsigned int p1 = (unsigned)o[2] | ((unsigned)o[3] << 16);
  *(uint2*)(out + (size_t)row * 1024 + tid * 4) = make_uint2(p0, p1);
}

// ---------------- bf16 MFMA GEMM, 128x128 tile, BK=32, fused epilogues ------
enum { EPI_QF = 0, EPI_KF = 1, EPI_V = 2, EPI_WO = 3, EPI_W1 = 4, EPI_W2 = 5 };

template <int EPI>
__global__ __launch_bounds__(256) void gemm_bf16(
    const unsigned short* __restrict__ A,   // [M][K] bf16
    const unsigned short* __restrict__ BT,  // [N][K] bf16 (pre-transposed)
    const float* __restrict__ bias, const float* __restrict__ res,
    const int* __restrict__ mask,
    float* __restrict__ outF, unsigned short* __restrict__ outB,
    int M, int N, int K)
{
  __shared__ __align__(16) unsigned short lA[128][40];  // pad->80B rows, 16B-aligned frags
  __shared__ __align__(16) unsigned short lB[128][40];
  const int tid = threadIdx.x;
  const int bn0 = blockIdx.x * 128, bm0 = blockIdx.y * 128;
  const int w = tid >> 6, l = tid & 63;
  const int wm = (w >> 1) * 64, wn = (w & 1) * 64;   // 2x2 waves, 64x64 each
  const int r16 = l & 15, g = l >> 4;
  const int stRow = tid >> 2;                 // 0..63
  const int stCol = (tid & 3) << 3;           // 0,8,16,24
  f32x4 acc[4][4] = {};

  for (int kt = 0; kt < K; kt += 32) {
    __syncthreads();
    {
      const int4 a0 = *(const int4*)&A[(size_t)(bm0 + stRow) * K + kt + stCol];
      const int4 a1 = *(const int4*)&A[(size_t)(bm0 + stRow + 64) * K + kt + stCol];
      const int4 b0 = *(const int4*)&BT[(size_t)(bn0 + stRow) * K + kt + stCol];
      const int4 b1 = *(const int4*)&BT[(size_t)(bn0 + stRow + 64) * K + kt + stCol];
      *(int4*)&lA[stRow][stCol] = a0;
      *(int4*)&lA[stRow + 64][stCol] = a1;
      *(int4*)&lB[stRow][stCol] = b0;
      *(int4*)&lB[stRow + 64][stCol] = b1;
    }
    __syncthreads();
    bf16x8 av[4], bv[4];
#pragma unroll
    for (int mi = 0; mi < 4; ++mi)
      av[mi] = __builtin_bit_cast(bf16x8, *(const us8*)&lA[wm + mi * 16 + r16][g * 8]);
#pragma unroll
    for (int ni = 0; ni < 4; ++ni)
      bv[ni] = __builtin_bit_cast(bf16x8, *(const us8*)&lB[wn + ni * 16 + r16][g * 8]);
#pragma unroll
    for (int mi = 0; mi < 4; ++mi)
#pragma unroll
      for (int ni = 0; ni < 4; ++ni)
        acc[mi][ni] = __builtin_amdgcn_mfma_f32_16x16x32_bf16(av[mi], bv[ni], acc[mi][ni], 0, 0, 0);
  }

#pragma unroll
  for (int mi = 0; mi < 4; ++mi) {
#pragma unroll
    for (int ni = 0; ni < 4; ++ni) {
#pragma unroll
      for (int r = 0; r < 4; ++r) {
        const int grow = bm0 + wm + mi * 16 + g * 4 + r;  // C/D: col=lane&15, row=(lane>>4)*4+reg
        const int gcol = bn0 + wn + ni * 16 + r16;
        const size_t o = (size_t)grow * N + gcol;
        const float v = acc[mi][ni][r];
        if constexpr (EPI == EPI_QF)      outF[o] = phi_fn(v);
        else if constexpr (EPI == EPI_KF) outF[o] = phi_fn(v) * (float)mask[grow];
        else if constexpr (EPI == EPI_V)  outF[o] = v * (float)mask[grow];
        else if constexpr (EPI == EPI_WO) outF[o] = v + res[o];
        else if constexpr (EPI == EPI_W1) {
          const float t = v + bias[gcol];
          outB[o] = f2bf(0.5f * t * (1.f + erff(t * 0.70710678118654752f)));
        } else if constexpr (EPI == EPI_W2) outF[o] = v + bias[gcol] + res[o];
      }
    }
  }
}

// ---------------- attention phase 1: per-chunk K^T V and sum(k) -------------
// grid 512 = (b*H+h)*16 + c ; chunk = 64 timesteps
__global__ __launch_bounds__(256) void chunk_sums(
    const float* __restrict__ kf, const float* __restrict__ v,
    float* __restrict__ S, float* __restrict__ z)
{
  __shared__ float kS[64][68];
  __shared__ float vS[64][68];
  const int blk = blockIdx.x;
  const int bh = blk >> 4, c = blk & 15;
  const int b = bh >> 4, h = bh & 15;
  const int tid = threadIdx.x;
  const size_t base = ((size_t)(b * 1024 + c * 64)) * 1024 + h * 64;
  for (int it = 0; it < 16; ++it) {
    const int lin = it * 256 + tid;
    const int t = lin >> 6, f = lin & 63;
    kS[t][f] = kf[base + (size_t)t * 1024 + f];
    vS[t][f] = v[base + (size_t)t * 1024 + f];
  }
  __syncthreads();
  const int fq = tid >> 2, dg = (tid & 3) * 16;
  float acc[16] = {};
  for (int t = 0; t < 64; ++t) {
    const float kk = kS[t][fq];
#pragma unroll
    for (int j = 0; j < 4; ++j) {
      const float4 vv = *(const float4*)&vS[t][dg + j * 4];
      acc[j*4+0] += kk * vv.x; acc[j*4+1] += kk * vv.y;
      acc[j*4+2] += kk * vv.z; acc[j*4+3] += kk * vv.w;
    }
  }
  float* Sp = S + ((size_t)bh * 16 + c) * 4096;
#pragma unroll
  for (int i = 0; i < 16; ++i) Sp[(size_t)fq * 64 + dg + i] = acc[i];
  if (tid < 64) {
    float s = 0.f;
    for (int t = 0; t < 64; ++t) s += kS[t][tid];
    z[((size_t)bh * 16 + c) * 64 + tid] = s;
  }
}

// ---------------- attention phase 2: in-place exclusive scan over chunks ----
__global__ __launch_bounds__(256) void scan_chunks(
    float* __restrict__ S, float* __restrict__ z)
{
  const int bh = blockIdx.x;  // 32
  const int tid = threadIdx.x;
  float run[16];
#pragma unroll
  for (int i = 0; i < 16; ++i) run[i] = 0.f;
  float zrun = 0.f;
  for (int c = 0; c < 16; ++c) {
    float* Sp = S + ((size_t)bh * 16 + c) * 4096;
#pragma unroll
    for (int i = 0; i < 16; ++i) {
      const int idx = i * 256 + tid;
      const float cur = Sp[idx];
      Sp[idx] = run[i];
      run[i] += cur;
    }
    if (tid < 64) {
      float* zp = z + ((size_t)bh * 16 + c) * 64;
      const float cur = zp[tid];
      zp[tid] = zrun;
      zrun += cur;
    }
  }
}

// ---------------- attention phase 3: per-chunk output -----------------------
// out[t][d] = (qf[t]·Sprev[:,d] + sum_{t'<=t} P[t][t'] v[t'][d]) / (den+eps)
// den[t]    =  qf[t]·zprev + rowsum_{t'<=t} P[t][t'],   P = qf kf^T
__global__ __launch_bounds__(256) void attn_out_kernel(
    const float* __restrict__ qf, const float* __restrict__ kf,
    const float* __restrict__ v, const float* __restrict__ Sp,
    const float* __restrict__ zp, unsigned short* __restrict__ attnB)
{
  __shared__ float qS[64][68];
  __shared__ float kvS[64][68];   // holds kf, then reused for v
  __shared__ float pS[64][68];
  __shared__ float zS[64];
  __shared__ float den[64];
  const int blk = blockIdx.x;
  const int bh = blk >> 4, c = blk & 15;
  const int b = bh >> 4, h = bh & 15;
  const int tid = threadIdx.x;
  const size_t base = ((size_t)(b * 1024 + c * 64)) * 1024 + h * 64;

  for (int it = 0; it < 16; ++it) {
    const int lin = it * 256 + tid;
    const int t = lin >> 6, f = lin & 63;
    qS[t][f] = qf[base + (size_t)t * 1024 + f];
    kvS[t][f] = kf[base + (size_t)t * 1024 + f];
  }
  if (tid < 64) zS[tid] = zp[((size_t)bh * 16 + c) * 64 + tid];
  __syncthreads();

  const int tr = tid >> 4, tc = tid & 15;   // 4x4 register tile per thread
  float p[4][4] = {};
  for (int f = 0; f < 64; ++f) {
    float qv[4], kv[4];
#pragma unroll
    for (int i = 0; i < 4; ++i) { qv[i] = qS[tr*4+i][f]; kv[i] = kvS[tc*4+i][f]; }
#pragma unroll
    for (int i = 0; i < 4; ++i)
#pragma unroll
      for (int j = 0; j < 4; ++j) p[i][j] += qv[i] * kv[j];
  }
#pragma unroll
  for (int i = 0; i < 4; ++i)
#pragma unroll
    for (int j = 0; j < 4; ++j) {
      const int t = tr*4 + i, t2 = tc*4 + j;
      pS[t][t2] = (t2 <= t) ? p[i][j] : 0.f;   // causal mask
    }
  __syncthreads();
  for (int it = 0; it < 16; ++it) {          // overwrite kf-buffer with v
    const int lin = it * 256 + tid;
    const int t = lin >> 6, f = lin & 63;
    kvS[t][f] = v[base + (size_t)t * 1024 + f];
  }
  if (tid < 64) {
    const int t = tid;
    float d = 0.f;
    for (int f = 0; f < 64; ++f) d += qS[t][f] * zS[f];
    for (int t2 = 0; t2 <= t; ++t2) d += pS[t][t2];
    den[t] = d + 1e-6f;
  }
  __syncthreads();

  const float* SpB = Sp + ((size_t)bh * 16 + c) * 4096;  // [f][d]
  float o[4][4] = {};
  for (int f = 0; f < 64; ++f) {
    float qv[4];
#pragma unroll
    for (int i = 0; i < 4; ++i) qv[i] = qS[tr*4+i][f];
    const float4 sv = *(const float4*)&SpB[(size_t)f * 64 + tc * 4];
#pragma unroll
    for (int i = 0; i < 4; ++i) {
      o[i][0] += qv[i]*sv.x; o[i][1] += qv[i]*sv.y;
      o[i][2] += qv[i]*sv.z; o[i][3] += qv[i]*sv.w;
    }
  }
  for (int t2 = 0; t2 < 64; ++t2) {
    float pv[4];
#pragma unroll
    for (int i = 0; i < 4; ++i) pv[i] = pS[tr*4+i][t2];
    const float4 vv = *(const float4*)&kvS[t2][tc * 4];
#pragma unroll
    for (int i = 0; i < 4; ++i) {
      o[i][0] += pv[i]*vv.x; o[i][1] += pv[i]*vv.y;
      o[i][2] += pv[i]*vv.z; o[i][3] += pv[i]*vv.w;
    }
  }
#pragma unroll
  for (int i = 0; i < 4; ++i) {
    const int t = tr*4 + i;
    const float dinv = 1.f / den[t];
#pragma unroll
    for (int j = 0; j < 4; ++j)
      attnB[base + (size_t)t * 1024 + tc * 4 + j] = f2bf(o[i][j] * dinv);
  }
}

// ---------------------------------------------------------------------------
extern "C" void kernel_launch(void* const* d_in, const int* in_sizes, int n_in,
                              void* d_out, int out_size, void* d_ws, size_t ws_size,
                              hipStream_t stream)
{
  (void)in_sizes; (void)n_in; (void)out_size; (void)ws_size;
  const float* x   = (const float*)d_in[0];
  const int*   msk = (const int*)d_in[1];
  const float* Wq  = (const float*)d_in[2];
  const float* Wk  = (const float*)d_in[3];
  const float* Wv  = (const float*)d_in[4];
  const float* Wo  = (const float*)d_in[5];
  const float* g1  = (const float*)d_in[6];
  const float* be1 = (const float*)d_in[7];
  const float* g2  = (const float*)d_in[8];
  const float* be2 = (const float*)d_in[9];
  const float* W1  = (const float*)d_in[10];
  const float* b1  = (const float*)d_in[11];
  const float* W2  = (const float*)d_in[12];
  const float* b2  = (const float*)d_in[13];
  float* out = (float*)d_out;

  char* ws = (char*)d_ws;
  const size_t MB = 1024 * 1024;
  unsigned short* WqT = (unsigned short*)(ws + 0 * MB);   // [1024][1024] bf16
  unsigned short* WkT = (unsigned short*)(ws + 2 * MB);
  unsigned short* WvT = (unsigned short*)(ws + 4 * MB);
  unsigned short* WoT = (unsigned short*)(ws + 6 * MB);
  unsigned short* W1T = (unsigned short*)(ws + 8 * MB);   // [4096][1024]
  unsigned short* W2T = (unsigned short*)(ws + 16 * MB);  // [1024][4096]
  unsigned short* hB  = (unsigned short*)(ws + 24 * MB);  // LN1 out bf16
  float* qf   = (float*)(ws + 28 * MB);                   // [2048][1024] fp32
  float* kf   = (float*)(ws + 36 * MB);
  float* vv   = (float*)(ws + 44 * MB);
  float* Ssum = (float*)(ws + 52 * MB);                   // [32][16][64][64]
  float* zsum = (float*)(ws + 60 * MB);                   // [32][16][64]
  unsigned short* attnB = (unsigned short*)(ws + 61 * MB);// [2048][1024] bf16
  float* x2   = (float*)(ws + 65 * MB);                   // [2048][1024] fp32
  unsigned short* h2B = (unsigned short*)(ws + 73 * MB);  // LN2 out bf16
  unsigned short* ffB = (unsigned short*)(ws + 77 * MB);  // [2048][4096] bf16
  // total ws usage: 93 MiB

  const dim3 B256(256);
  cvt_transpose<<<dim3(16, 16), B256, 0, stream>>>(Wq, WqT, 1024, 1024);
  cvt_transpose<<<dim3(16, 16), B256, 0, stream>>>(Wk, WkT, 1024, 1024);
  cvt_transpose<<<dim3(16, 16), B256, 0, stream>>>(Wv, WvT, 1024, 1024);
  cvt_transpose<<<dim3(16, 16), B256, 0, stream>>>(Wo, WoT, 1024, 1024);
  cvt_transpose<<<dim3(64, 16), B256, 0, stream>>>(W1, W1T, 1024, 4096);
  cvt_transpose<<<dim3(16, 64), B256, 0, stream>>>(W2, W2T, 4096, 1024);

  ln_to_bf16<<<2048, B256, 0, stream>>>(x, g1, be1, hB);

  gemm_bf16<EPI_QF><<<dim3(8, 16), B256, 0, stream>>>(hB, WqT, nullptr, nullptr, nullptr, qf, nullptr, 2048, 1024, 1024);
  gemm_bf16<EPI_KF><<<dim3(8, 16), B256, 0, stream>>>(hB, WkT, nullptr, nullptr, msk, kf, nullptr, 2048, 1024, 1024);
  gemm_bf16<EPI_V ><<<dim3(8, 16), B256, 0, stream>>>(hB, WvT, nullptr, nullptr, msk, vv, nullptr, 2048, 1024, 1024);

  chunk_sums<<<512, B256, 0, stream>>>(kf, vv, Ssum, zsum);
  scan_chunks<<<32, B256, 0, stream>>>(Ssum, zsum);
  attn_out_kernel<<<512, B256, 0, stream>>>(qf, kf, vv, Ssum, zsum, attnB);

  gemm_bf16<EPI_WO><<<dim3(8, 16), B256, 0, stream>>>(attnB, WoT, nullptr, x, nullptr, x2, nullptr, 2048, 1024, 1024);

  ln_to_bf16<<<2048, B256, 0, stream>>>(x2, g2, be2, h2B);

  gemm_bf16<EPI_W1><<<dim3(32, 16), B256, 0, stream>>>(h2B, W1T, b1, nullptr, nullptr, nullptr, ffB, 2048, 4096, 1024);
  gemm_bf16<EPI_W2><<<dim3(8, 16), B256, 0, stream>>>(ffB, W2T, b2, x2, nullptr, out, nullptr, 2048, 1024, 4096);
}

// Round 2
// 304.270 us; speedup vs baseline: 1.3206x; 1.3206x over previous
//
#include <hip/hip_runtime.h>
#include <math.h>

// ---------------------------------------------------------------------------
// LinearBlock: LN -> fused QKV GEMM -> causal linear attention (elu+1)
//              -> Wo+res -> LN -> GELU MLP + res.
// B=2 T=1024 D=1024 H=16 DH=64 FF=4096.  bf16 MFMA GEMMs (fp32 accum),
// global_load_lds staging (m97 structure), fp32 chunked linear attention.
// ---------------------------------------------------------------------------

typedef __attribute__((ext_vector_type(8))) __bf16 bf16x8;
typedef __attribute__((ext_vector_type(8))) unsigned short us8;
typedef __attribute__((ext_vector_type(4))) float f32x4;

__device__ __forceinline__ unsigned short f2bf(float f) {
  unsigned int u = __builtin_bit_cast(unsigned int, f);
  unsigned int r = (u + 0x7fffu + ((u >> 16) & 1u)) >> 16;  // RNE
  return (unsigned short)r;
}
__device__ __forceinline__ float phi_fn(float x) {  // elu(x)+1
  return x > 0.f ? x + 1.f : __expf(x);
}

// async global->LDS, 16B per lane; LDS dest is wave-uniform base + lane*16
__device__ __forceinline__ void gload16(const unsigned short* g, unsigned short* l) {
  __builtin_amdgcn_global_load_lds(
      (const __attribute__((address_space(1))) unsigned int*)(const void*)g,
      (__attribute__((address_space(3))) unsigned int*)(void*)l, 16, 0, 0);
}

// ---------------- weight convert + transpose (all weights, one dispatch) ----
__device__ __forceinline__ void cvt_tile(
    const float* __restrict__ W, unsigned short* __restrict__ WT,
    int K, int N, int tk, int tn, int tid)
{
  __shared__ unsigned short tile[64][72];
  const int n0 = tn * 64, k0 = tk * 64;
  for (int it = 0; it < 16; ++it) {
    const int lin = it * 256 + tid;
    const int i = lin >> 6, j = lin & 63;            // i: k, j: n
    tile[j][i] = f2bf(W[(size_t)(k0 + i) * N + n0 + j]);
  }
  __syncthreads();
  for (int it = 0; it < 16; ++it) {
    const int lin = it * 256 + tid;
    const int j = lin >> 6, i = lin & 63;
    WT[(size_t)(n0 + j) * K + k0 + i] = tile[j][i];
  }
}

__global__ __launch_bounds__(256) void cvt_all(
    const float* __restrict__ Wq, const float* __restrict__ Wk,
    const float* __restrict__ Wv, const float* __restrict__ Wo,
    const float* __restrict__ W1, const float* __restrict__ W2,
    unsigned short* __restrict__ WqkvT, unsigned short* __restrict__ WoT,
    unsigned short* __restrict__ W1T, unsigned short* __restrict__ W2T)
{
  const int bid = blockIdx.x, tid = threadIdx.x;
  if (bid < 768) {                    // Wq,Wk,Wv -> stacked [3072][1024]
    const int wsel = bid >> 8, local = bid & 255;
    const float* W = wsel == 0 ? Wq : (wsel == 1 ? Wk : Wv);
    cvt_tile(W, WqkvT + (size_t)wsel * 1024 * 1024, 1024, 1024, local >> 4, local & 15, tid);
  } else if (bid < 1024) {
    const int local = bid - 768;
    cvt_tile(Wo, WoT, 1024, 1024, local >> 4, local & 15, tid);
  } else if (bid < 2048) {            // W1: [1024][4096] -> [4096][1024]
    const int local = bid - 1024;
    cvt_tile(W1, W1T, 1024, 4096, local >> 6, local & 63, tid);
  } else {                            // W2: [4096][1024] -> [1024][4096]
    const int local = bid - 2048;
    cvt_tile(W2, W2T, 4096, 1024, local >> 4, local & 15, tid);
  }
}

// ---------------- LayerNorm (D=1024) fp32 in -> bf16 out --------------------
__global__ __launch_bounds__(256) void ln_to_bf16(
    const float* __restrict__ x, const float* __restrict__ g,
    const float* __restrict__ b, unsigned short* __restrict__ out)
{
  const int row = blockIdx.x;
  const int tid = threadIdx.x;
  const float4 xv = *(const float4*)&x[(size_t)row * 1024 + tid * 4];
  float xa[4] = {xv.x, xv.y, xv.z, xv.w};
  float s = xa[0] + xa[1] + xa[2] + xa[3];
  float sq = xa[0]*xa[0] + xa[1]*xa[1] + xa[2]*xa[2] + xa[3]*xa[3];
  for (int off = 32; off > 0; off >>= 1) {
    s += __shfl_down(s, off);
    sq += __shfl_down(sq, off);
  }
  __shared__ float red[8];
  if ((tid & 63) == 0) { red[tid >> 6] = s; red[4 + (tid >> 6)] = sq; }
  __syncthreads();
  const float ts = red[0] + red[1] + red[2] + red[3];
  const float tq = red[4] + red[5] + red[6] + red[7];
  const float mean = ts * (1.f / 1024.f);
  const float var = tq * (1.f / 1024.f) - mean * mean;
  const float inv = rsqrtf(var + 1e-5f);
  unsigned short o[4];
#pragma unroll
  for (int j = 0; j < 4; ++j) {
    const int col = tid * 4 + j;
    o[j] = f2bf((xa[j] - mean) * inv * g[col] + b[col]);
  }
  unsigned int p0 = (unsigned)o[0] | ((unsigned)o[1] << 16);
  unsigned int p1 = (unsigned)o[2] | ((unsigned)o[3] << 16);
  *(uint2*)(out + (size_t)row * 1024 + tid * 4) = make_uint2(p0, p1);
}

// ---------------- bf16 MFMA GEMM, BMx BN tile, BK=32, global_load_lds -------
enum { EPI_QKV = 0, EPI_WO = 1, EPI_W1 = 2, EPI_PART = 3 };

template <int BM, int BN, int EPI>
__global__ __launch_bounds__(256) void gemm_bf16(
    const unsigned short* __restrict__ A,   // [M][lda] bf16
    const unsigned short* __restrict__ BT,  // [N][ldb] bf16 (pre-transposed)
    const float* __restrict__ bias, const float* __restrict__ res,
    const int* __restrict__ mask,
    float* __restrict__ outF, unsigned short* __restrict__ outB,
    int M, int N, int K, int lda, int ldb)
{
  constexpr int FM = BM / 32, FN = BN / 32;   // 16x16 frags per wave
  constexpr int IA = BM / 64, IB = BN / 64;   // gload issues per thread
  __shared__ __align__(16) unsigned short lA[BM * 32];  // [BM][32] linear
  __shared__ __align__(16) unsigned short lB[BN * 32];
  const int tid = threadIdx.x;
  const int bn0 = blockIdx.x * BN, bm0 = blockIdx.y * BM;
  const int kz = blockIdx.z;                  // split-K slice
  A  += (size_t)kz * K;
  BT += (size_t)kz * K;
  if constexpr (EPI == EPI_PART) outF += (size_t)kz * M * N;

  const int w = tid >> 6, l = tid & 63;
  const int wm = (w >> 1) * (BM / 2), wn = (w & 1) * (BN / 2);
  const int r16 = l & 15, g = l >> 4;
  const int srow = l >> 2, scol = (l & 3) * 8;
  f32x4 acc[FM][FN] = {};

  const unsigned short* Ab = A + (size_t)bm0 * lda;
  const unsigned short* Bb = BT + (size_t)bn0 * ldb;

  for (int kt = 0; kt < K; kt += 32) {
#pragma unroll
    for (int i = 0; i < IA; ++i) {
      const int r0 = (w * IA + i) * 16;
      gload16(&Ab[(size_t)(r0 + srow) * lda + kt + scol], &lA[r0 * 32]);
    }
#pragma unroll
    for (int i = 0; i < IB; ++i) {
      const int r0 = (w * IB + i) * 16;
      gload16(&Bb[(size_t)(r0 + srow) * ldb + kt + scol], &lB[r0 * 32]);
    }
    __syncthreads();   // drains vmcnt (gload_lds) before ds_read
    bf16x8 av[FM], bv[FN];
#pragma unroll
    for (int mi = 0; mi < FM; ++mi)
      av[mi] = __builtin_bit_cast(bf16x8, *(const us8*)&lA[(wm + mi * 16 + r16) * 32 + g * 8]);
#pragma unroll
    for (int ni = 0; ni < FN; ++ni)
      bv[ni] = __builtin_bit_cast(bf16x8, *(const us8*)&lB[(wn + ni * 16 + r16) * 32 + g * 8]);
#pragma unroll
    for (int mi = 0; mi < FM; ++mi)
#pragma unroll
      for (int ni = 0; ni < FN; ++ni)
        acc[mi][ni] = __builtin_amdgcn_mfma_f32_16x16x32_bf16(av[mi], bv[ni], acc[mi][ni], 0, 0, 0);
    __syncthreads();   // protect LDS before next stage overwrites
  }

#pragma unroll
  for (int mi = 0; mi < FM; ++mi) {
#pragma unroll
    for (int r = 0; r < 4; ++r) {
      const int grow = bm0 + wm + mi * 16 + g * 4 + r;  // C/D: col=lane&15, row=(lane>>4)*4+reg
      float mrow = 0.f;
      if constexpr (EPI == EPI_QKV) mrow = (float)mask[grow];
#pragma unroll
      for (int ni = 0; ni < FN; ++ni) {
        const int gcol = bn0 + wn + ni * 16 + r16;
        const size_t o = (size_t)grow * N + gcol;
        const float v = acc[mi][ni][r];
        if constexpr (EPI == EPI_QKV) {
          const int seg = (bn0 + wn + ni * 16) >> 10;   // 0:q 1:k 2:v
          outF[o] = (seg == 0) ? phi_fn(v) : (seg == 1 ? phi_fn(v) * mrow : v * mrow);
        } else if constexpr (EPI == EPI_WO) {
          outF[o] = v + res[o];
        } else if constexpr (EPI == EPI_W1) {
          const float t = v + bias[gcol];
          outB[o] = f2bf(0.5f * t * (1.f + erff(t * 0.70710678118654752f)));
        } else if constexpr (EPI == EPI_PART) {
          outF[o] = v;
        }
      }
    }
  }
}

// ---------------- split-K reduce for W2: out = p0+p1+bias+res ---------------
__global__ __launch_bounds__(256) void reduce_w2(
    const float* __restrict__ part, const float* __restrict__ res,
    const float* __restrict__ bias, float* __restrict__ out)
{
  const int row = blockIdx.x, tid = threadIdx.x;
  const size_t o = (size_t)row * 1024 + tid * 4;
  const float4 p0 = *(const float4*)&part[o];
  const float4 p1 = *(const float4*)&part[(size_t)2048 * 1024 + o];
  const float4 r = *(const float4*)&res[o];
  const float4 b = *(const float4*)&bias[tid * 4];
  float4 s;
  s.x = p0.x + p1.x + r.x + b.x;
  s.y = p0.y + p1.y + r.y + b.y;
  s.z = p0.z + p1.z + r.z + b.z;
  s.w = p0.w + p1.w + r.w + b.w;
  *(float4*)&out[o] = s;
}

// ---------------- attention phase 1: per-chunk K^T V and sum(k) -------------
// qkv layout: [2048][3072] fp32, segments q|k|v of 1024 each.
__global__ __launch_bounds__(256) void chunk_sums(
    const float* __restrict__ qkv, float* __restrict__ S, float* __restrict__ z)
{
  __shared__ float kS[64][68];
  __shared__ float vS[64][68];
  const int blk = blockIdx.x;
  const int bh = blk >> 4, c = blk & 15;
  const int b = bh >> 4, h = bh & 15;
  const int tid = threadIdx.x;
  const size_t base = ((size_t)(b * 1024 + c * 64)) * 3072 + h * 64;
  for (int it = 0; it < 16; ++it) {
    const int lin = it * 256 + tid;
    const int t = lin >> 6, f = lin & 63;
    kS[t][f] = qkv[base + 1024 + (size_t)t * 3072 + f];
    vS[t][f] = qkv[base + 2048 + (size_t)t * 3072 + f];
  }
  __syncthreads();
  const int fq = tid >> 2, dg = (tid & 3) * 16;
  float acc[16] = {};
  for (int t = 0; t < 64; ++t) {
    const float kk = kS[t][fq];
#pragma unroll
    for (int j = 0; j < 4; ++j) {
      const float4 vv = *(const float4*)&vS[t][dg + j * 4];
      acc[j*4+0] += kk * vv.x; acc[j*4+1] += kk * vv.y;
      acc[j*4+2] += kk * vv.z; acc[j*4+3] += kk * vv.w;
    }
  }
  float* Sp = S + ((size_t)bh * 16 + c) * 4096;
#pragma unroll
  for (int i = 0; i < 16; ++i) Sp[(size_t)fq * 64 + dg + i] = acc[i];
  if (tid < 64) {
    float s = 0.f;
    for (int t = 0; t < 64; ++t) s += kS[t][tid];
    z[((size_t)bh * 16 + c) * 64 + tid] = s;
  }
}

// ---------------- attention phase 2: in-place exclusive scan over chunks ----
__global__ __launch_bounds__(256) void scan_chunks(
    float* __restrict__ S, float* __restrict__ z)
{
  const int bh = blockIdx.x;  // 32
  const int tid = threadIdx.x;
  float run[16];
#pragma unroll
  for (int i = 0; i < 16; ++i) run[i] = 0.f;
  float zrun = 0.f;
  for (int c = 0; c < 16; ++c) {
    float* Sp = S + ((size_t)bh * 16 + c) * 4096;
#pragma unroll
    for (int i = 0; i < 16; ++i) {
      const int idx = i * 256 + tid;
      const float cur = Sp[idx];
      Sp[idx] = run[i];
      run[i] += cur;
    }
    if (tid < 64) {
      float* zp = z + ((size_t)bh * 16 + c) * 64;
      const float cur = zp[tid];
      zp[tid] = zrun;
      zrun += cur;
    }
  }
}

// ---------------- attention phase 3: per-chunk output -----------------------
__global__ __launch_bounds__(256) void attn_out_kernel(
    const float* __restrict__ qkv, const float* __restrict__ Sp,
    const float* __restrict__ zp, unsigned short* __restrict__ attnB)
{
  __shared__ float qS[64][68];
  __shared__ float kvS[64][68];   // holds kf, then reused for v
  __shared__ float pS[64][68];
  __shared__ float zS[64];
  __shared__ float den[64];
  const int blk = blockIdx.x;
  const int bh = blk >> 4, c = blk & 15;
  const int b = bh >> 4, h = bh & 15;
  const int tid = threadIdx.x;
  const size_t base = ((size_t)(b * 1024 + c * 64)) * 3072 + h * 64;
  const size_t obase = ((size_t)(b * 1024 + c * 64)) * 1024 + h * 64;

  for (int it = 0; it < 16; ++it) {
    const int lin = it * 256 + tid;
    const int t = lin >> 6, f = lin & 63;
    qS[t][f] = qkv[base + (size_t)t * 3072 + f];
    kvS[t][f] = qkv[base + 1024 + (size_t)t * 3072 + f];
  }
  if (tid < 64) zS[tid] = zp[((size_t)bh * 16 + c) * 64 + tid];
  __syncthreads();

  const int tr = tid >> 4, tc = tid & 15;   // 4x4 register tile per thread
  float p[4][4] = {};
  for (int f = 0; f < 64; ++f) {
    float qv[4], kv[4];
#pragma unroll
    for (int i = 0; i < 4; ++i) { qv[i] = qS[tr*4+i][f]; kv[i] = kvS[tc*4+i][f]; }
#pragma unroll
    for (int i = 0; i < 4; ++i)
#pragma unroll
      for (int j = 0; j < 4; ++j) p[i][j] += qv[i] * kv[j];
  }
#pragma unroll
  for (int i = 0; i < 4; ++i)
#pragma unroll
    for (int j = 0; j < 4; ++j) {
      const int t = tr*4 + i, t2 = tc*4 + j;
      pS[t][t2] = (t2 <= t) ? p[i][j] : 0.f;   // causal mask
    }
  __syncthreads();
  for (int it = 0; it < 16; ++it) {          // overwrite kf-buffer with v
    const int lin = it * 256 + tid;
    const int t = lin >> 6, f = lin & 63;
    kvS[t][f] = qkv[base + 2048 + (size_t)t * 3072 + f];
  }
  if (tid < 64) {
    const int t = tid;
    float d = 0.f;
    for (int f = 0; f < 64; ++f) d += qS[t][f] * zS[f];
    for (int t2 = 0; t2 <= t; ++t2) d += pS[t][t2];
    den[t] = d + 1e-6f;
  }
  __syncthreads();

  const float* SpB = Sp + ((size_t)bh * 16 + c) * 4096;  // [f][d]
  float o[4][4] = {};
  for (int f = 0; f < 64; ++f) {
    float qv[4];
#pragma unroll
    for (int i = 0; i < 4; ++i) qv[i] = qS[tr*4+i][f];
    const float4 sv = *(const float4*)&SpB[(size_t)f * 64 + tc * 4];
#pragma unroll
    for (int i = 0; i < 4; ++i) {
      o[i][0] += qv[i]*sv.x; o[i][1] += qv[i]*sv.y;
      o[i][2] += qv[i]*sv.z; o[i][3] += qv[i]*sv.w;
    }
  }
  for (int t2 = 0; t2 < 64; ++t2) {
    float pv[4];
#pragma unroll
    for (int i = 0; i < 4; ++i) pv[i] = pS[tr*4+i][t2];
    const float4 vv = *(const float4*)&kvS[t2][tc * 4];
#pragma unroll
    for (int i = 0; i < 4; ++i) {
      o[i][0] += pv[i]*vv.x; o[i][1] += pv[i]*vv.y;
      o[i][2] += pv[i]*vv.z; o[i][3] += pv[i]*vv.w;
    }
  }
#pragma unroll
  for (int i = 0; i < 4; ++i) {
    const int t = tr*4 + i;
    const float dinv = 1.f / den[t];
#pragma unroll
    for (int j = 0; j < 4; ++j)
      attnB[obase + (size_t)t * 1024 + tc * 4 + j] = f2bf(o[i][j] * dinv);
  }
}

// ---------------------------------------------------------------------------
extern "C" void kernel_launch(void* const* d_in, const int* in_sizes, int n_in,
                              void* d_out, int out_size, void* d_ws, size_t ws_size,
                              hipStream_t stream)
{
  (void)in_sizes; (void)n_in; (void)out_size; (void)ws_size;
  const float* x   = (const float*)d_in[0];
  const int*   msk = (const int*)d_in[1];
  const float* Wq  = (const float*)d_in[2];
  const float* Wk  = (const float*)d_in[3];
  const float* Wv  = (const float*)d_in[4];
  const float* Wo  = (const float*)d_in[5];
  const float* g1  = (const float*)d_in[6];
  const float* be1 = (const float*)d_in[7];
  const float* g2  = (const float*)d_in[8];
  const float* be2 = (const float*)d_in[9];
  const float* W1  = (const float*)d_in[10];
  const float* b1  = (const float*)d_in[11];
  const float* W2  = (const float*)d_in[12];
  const float* b2  = (const float*)d_in[13];
  float* out = (float*)d_out;

  char* ws = (char*)d_ws;
  const size_t MB = 1024 * 1024;
  unsigned short* WqkvT = (unsigned short*)(ws + 0 * MB);   // [3072][1024] bf16
  unsigned short* WoT   = (unsigned short*)(ws + 6 * MB);   // [1024][1024]
  unsigned short* W1T   = (unsigned short*)(ws + 8 * MB);   // [4096][1024]
  unsigned short* W2T   = (unsigned short*)(ws + 16 * MB);  // [1024][4096]
  unsigned short* hB    = (unsigned short*)(ws + 24 * MB);  // LN1 out bf16
  float* qkv  = (float*)(ws + 28 * MB);                     // [2048][3072] fp32
  float* Ssum = (float*)(ws + 52 * MB);                     // [32][16][64][64]
  float* zsum = (float*)(ws + 60 * MB);                     // [32][16][64]
  unsigned short* attnB = (unsigned short*)(ws + 61 * MB);  // [2048][1024] bf16
  float* x2   = (float*)(ws + 65 * MB);                     // [2048][1024] fp32
  unsigned short* h2B = (unsigned short*)(ws + 73 * MB);    // LN2 out bf16
  unsigned short* ffB = (unsigned short*)(ws + 77 * MB);    // [2048][4096] bf16
  float* part = (float*)(ws + 28 * MB);                     // reuse qkv region post-attn: [2][2048][1024]

  const dim3 B256(256);
  cvt_all<<<3072, B256, 0, stream>>>(Wq, Wk, Wv, Wo, W1, W2, WqkvT, WoT, W1T, W2T);
  ln_to_bf16<<<2048, B256, 0, stream>>>(x, g1, be1, hB);

  gemm_bf16<128, 128, EPI_QKV><<<dim3(24, 16), B256, 0, stream>>>(
      hB, WqkvT, nullptr, nullptr, msk, qkv, nullptr, 2048, 3072, 1024, 1024, 1024);

  chunk_sums<<<512, B256, 0, stream>>>(qkv, Ssum, zsum);
  scan_chunks<<<32, B256, 0, stream>>>(Ssum, zsum);
  attn_out_kernel<<<512, B256, 0, stream>>>(qkv, Ssum, zsum, attnB);

  gemm_bf16<128, 64, EPI_WO><<<dim3(16, 16), B256, 0, stream>>>(
      attnB, WoT, nullptr, x, nullptr, x2, nullptr, 2048, 1024, 1024, 1024, 1024);

  ln_to_bf16<<<2048, B256, 0, stream>>>(x2, g2, be2, h2B);

  gemm_bf16<128, 128, EPI_W1><<<dim3(32, 16), B256, 0, stream>>>(
      h2B, W1T, b1, nullptr, nullptr, nullptr, ffB, 2048, 4096, 1024, 1024, 1024);

  // W2 split-K=2: partials then reduce (+bias +residual)
  gemm_bf16<128, 64, EPI_PART><<<dim3(16, 16, 2), B256, 0, stream>>>(
      ffB, W2T, nullptr, nullptr, nullptr, part, nullptr, 2048, 1024, 2048, 4096, 4096);
  reduce_w2<<<2048, B256, 0, stream>>>(part, x2, b2, out);
}

// Round 4
// 263.018 us; speedup vs baseline: 1.5277x; 1.1568x over previous
//
#include <hip/hip_runtime.h>
#include <math.h>

// ---------------------------------------------------------------------------
// LinearBlock: LN -> fused QKV GEMM -> causal linear attention (elu+1)
//              -> Wo+res -> LN -> GELU MLP + res.
// B=2 T=1024 D=1024 H=16 DH=64 FF=4096.
// GEMMs: bf16 MFMA, BK=64, double-buffered gload_lds w/ 1 barrier per step
// (T3 minimum 2-phase), XOR-swizzled LDS (pre-swizzled global src, rule #21),
// XCD-chunked block remap (T1, 2x4 super-tiles).  Attn: fp32 chunked scan.
// ---------------------------------------------------------------------------

typedef __attribute__((ext_vector_type(8))) __bf16 bf16x8;
typedef __attribute__((ext_vector_type(8))) unsigned short us8;
typedef __attribute__((ext_vector_type(4))) float f32x4;

__device__ __forceinline__ unsigned short f2bf(float f) {
  unsigned int u = __builtin_bit_cast(unsigned int, f);
  unsigned int r = (u + 0x7fffu + ((u >> 16) & 1u)) >> 16;  // RNE
  return (unsigned short)r;
}
__device__ __forceinline__ float bf2f(unsigned short u) {
  return __builtin_bit_cast(float, ((unsigned int)u) << 16);
}
__device__ __forceinline__ float phi_fn(float x) {  // elu(x)+1
  return x > 0.f ? x + 1.f : __expf(x);
}

// async global->LDS, 16B/lane; LDS dest = wave-uniform base + lane*16 (linear)
__device__ __forceinline__ void gload16(const unsigned short* g, unsigned short* l) {
  __builtin_amdgcn_global_load_lds(
      (const __attribute__((address_space(1))) unsigned int*)(const void*)g,
      (__attribute__((address_space(3))) unsigned int*)(void*)l, 16, 0, 0);
}

// ---------------- weight convert + transpose (all weights, one dispatch) ----
__device__ __forceinline__ void cvt_tile(
    const float* __restrict__ W, unsigned short* __restrict__ WT,
    int K, int N, int tk, int tn, int tid)
{
  __shared__ unsigned short tile[64][72];
  const int n0 = tn * 64, k0 = tk * 64;
  for (int it = 0; it < 16; ++it) {
    const int lin = it * 256 + tid;
    const int i = lin >> 6, j = lin & 63;            // i: k, j: n
    tile[j][i] = f2bf(W[(size_t)(k0 + i) * N + n0 + j]);
  }
  __syncthreads();
  for (int it = 0; it < 16; ++it) {
    const int lin = it * 256 + tid;
    const int j = lin >> 6, i = lin & 63;
    WT[(size_t)(n0 + j) * K + k0 + i] = tile[j][i];
  }
}

__global__ __launch_bounds__(256) void cvt_all(
    const float* __restrict__ Wq, const float* __restrict__ Wk,
    const float* __restrict__ Wv, const float* __restrict__ Wo,
    const float* __restrict__ W1, const float* __restrict__ W2,
    unsigned short* __restrict__ WqkvT, unsigned short* __restrict__ WoT,
    unsigned short* __restrict__ W1T, unsigned short* __restrict__ W2T)
{
  const int bid = blockIdx.x, tid = threadIdx.x;
  if (bid < 768) {                    // Wq,Wk,Wv -> stacked [3072][1024]
    const int wsel = bid >> 8, local = bid & 255;
    const float* W = wsel == 0 ? Wq : (wsel == 1 ? Wk : Wv);
    cvt_tile(W, WqkvT + (size_t)wsel * 1024 * 1024, 1024, 1024, local >> 4, local & 15, tid);
  } else if (bid < 1024) {
    const int local = bid - 768;
    cvt_tile(Wo, WoT, 1024, 1024, local >> 4, local & 15, tid);
  } else if (bid < 2048) {            // W1: [1024][4096] -> [4096][1024]
    const int local = bid - 1024;
    cvt_tile(W1, W1T, 1024, 4096, local >> 6, local & 63, tid);
  } else {                            // W2: [4096][1024] -> [1024][4096]
    const int local = bid - 2048;
    cvt_tile(W2, W2T, 4096, 1024, local >> 4, local & 15, tid);
  }
}

// ---------------- LayerNorm (D=1024) fp32 in -> bf16 out --------------------
__global__ __launch_bounds__(256) void ln_to_bf16(
    const float* __restrict__ x, const float* __restrict__ g,
    const float* __restrict__ b, unsigned short* __restrict__ out)
{
  const int row = blockIdx.x;
  const int tid = threadIdx.x;
  const float4 xv = *(const float4*)&x[(size_t)row * 1024 + tid * 4];
  float xa[4] = {xv.x, xv.y, xv.z, xv.w};
  float s = xa[0] + xa[1] + xa[2] + xa[3];
  float sq = xa[0]*xa[0] + xa[1]*xa[1] + xa[2]*xa[2] + xa[3]*xa[3];
  for (int off = 32; off > 0; off >>= 1) {
    s += __shfl_down(s, off);
    sq += __shfl_down(sq, off);
  }
  __shared__ float red[8];
  if ((tid & 63) == 0) { red[tid >> 6] = s; red[4 + (tid >> 6)] = sq; }
  __syncthreads();
  const float ts = red[0] + red[1] + red[2] + red[3];
  const float tq = red[4] + red[5] + red[6] + red[7];
  const float mean = ts * (1.f / 1024.f);
  const float var = tq * (1.f / 1024.f) - mean * mean;
  const float inv = rsqrtf(var + 1e-5f);
  unsigned short o[4];
#pragma unroll
  for (int j = 0; j < 4; ++j) {
    const int col = tid * 4 + j;
    o[j] = f2bf((xa[j] - mean) * inv * g[col] + b[col]);
  }
  unsigned int p0 = (unsigned)o[0] | ((unsigned)o[1] << 16);
  unsigned int p1 = (unsigned)o[2] | ((unsigned)o[3] << 16);
  *(uint2*)(out + (size_t)row * 1024 + tid * 4) = make_uint2(p0, p1);
}

// ---------------- bf16 MFMA GEMM: BK=64, dbuf, swizzled LDS, XCD remap ------
enum { EPI_QKV = 0, EPI_WO = 1, EPI_W1 = 2, EPI_PART = 3 };

template <int BM, int BN, int EPI>
__global__ __launch_bounds__(256) void gemm_bf16(
    const unsigned short* __restrict__ A,   // [M][lda] bf16
    const unsigned short* __restrict__ BT,  // [N][ldb] bf16 (pre-transposed)
    const float* __restrict__ bias, const float* __restrict__ res,
    const int* __restrict__ mask,
    float* __restrict__ outF, unsigned short* __restrict__ outB,
    int M, int N, int K, int lda, int ldb)
{
  constexpr int FM = BM / 32, FN = BN / 32;   // 16x16 frags per wave (per k-half)
  constexpr int IA = BM / 32, IB = BN / 32;   // 8-row gload issues per wave
  __shared__ __align__(16) unsigned short lA[2][BM * 64];  // [row][64] linear
  __shared__ __align__(16) unsigned short lB[2][BN * 64];
  const int tid = threadIdx.x;

  // XCD-chunked remap: 2(bm)x4(bn) super-tiles, one per 8-slot XCD chunk.
  int bn_i, bm_i;
  {
    const int gx = gridDim.x, gy = gridDim.y;
    const int i = blockIdx.x + blockIdx.y * gx;
    const int nwg = gx * gy;
    if (((nwg & 63) == 0) && ((gx & 3) == 0) && ((gy & 1) == 0)) {
      const int k8 = i & 7, j = i >> 3;
      const int G = k8 + (j >> 3) * 8;   // super-group id (G%8 == xcd)
      const int p = j & 7;
      const int sgx = gx >> 2;
      bm_i = (G / sgx) * 2 + (p >> 2);
      bn_i = (G % sgx) * 4 + (p & 3);
    } else { bn_i = blockIdx.x; bm_i = blockIdx.y; }
  }
  const int bn0 = bn_i * BN, bm0 = bm_i * BM;
  const int kz = blockIdx.z;                  // split-K slice
  A  += (size_t)kz * K;                       // col shift (lda covers it)
  BT += (size_t)kz * K;
  if constexpr (EPI == EPI_PART) outF += (size_t)kz * M * N;

  const int w = tid >> 6, l = tid & 63;
  const int wm = (w >> 1) * (BM / 2), wn = (w & 1) * (BN / 2);
  const int r16 = l & 15, g = l >> 4;
  // staging: 8 rows/issue; global col-group pre-XOR'd so linear LDS holds
  // swizzled layout (slot s of row r = col-group s^(r&7))
  const int srow8 = l >> 3;                        // 0..7
  const int scolg = ((l & 7) ^ srow8) * 8;         // element col in tile
  f32x4 acc[FM][FN] = {};

  const unsigned short* Ab = A + (size_t)bm0 * lda;
  const unsigned short* Bb = BT + (size_t)bn0 * ldb;
  const int nsteps = K >> 6;

  auto stage = [&](int s, int buf) {
    const int kc = s << 6;
#pragma unroll
    for (int ii = 0; ii < IA; ++ii) {
      const int r0 = (w * IA + ii) * 8;
      gload16(&Ab[(size_t)(r0 + srow8) * lda + kc + scolg], &lA[buf][r0 * 64]);
    }
#pragma unroll
    for (int ii = 0; ii < IB; ++ii) {
      const int r0 = (w * IB + ii) * 8;
      gload16(&Bb[(size_t)(r0 + srow8) * ldb + kc + scolg], &lB[buf][r0 * 64]);
    }
  };

  stage(0, 0);
  int cur = 0;
  for (int s = 0; s < nsteps; ++s) {
    __syncthreads();                 // drains vmcnt -> buf[cur] ready; alt free
    if (s + 1 < nsteps) stage(s + 1, cur ^ 1);   // async, overlaps compute
#pragma unroll
    for (int h = 0; h < 2; ++h) {
      bf16x8 av[FM], bv[FN];
#pragma unroll
      for (int mi = 0; mi < FM; ++mi) {
        const int row = wm + mi * 16 + r16;
        const int grp = (h * 4 + g) ^ (r16 & 7);
        av[mi] = __builtin_bit_cast(bf16x8, *(const us8*)&lA[cur][row * 64 + grp * 8]);
      }
#pragma unroll
      for (int ni = 0; ni < FN; ++ni) {
        const int row = wn + ni * 16 + r16;
        const int grp = (h * 4 + g) ^ (r16 & 7);
        bv[ni] = __builtin_bit_cast(bf16x8, *(const us8*)&lB[cur][row * 64 + grp * 8]);
      }
#pragma unroll
      for (int mi = 0; mi < FM; ++mi)
#pragma unroll
        for (int ni = 0; ni < FN; ++ni)
          acc[mi][ni] = __builtin_amdgcn_mfma_f32_16x16x32_bf16(av[mi], bv[ni], acc[mi][ni], 0, 0, 0);
    }
    cur ^= 1;
  }

#pragma unroll
  for (int mi = 0; mi < FM; ++mi) {
#pragma unroll
    for (int r = 0; r < 4; ++r) {
      const int grow = bm0 + wm + mi * 16 + g * 4 + r;  // C/D: col=lane&15, row=(lane>>4)*4+reg
      float mrow = 0.f;
      if constexpr (EPI == EPI_QKV) mrow = (float)mask[grow];
#pragma unroll
      for (int ni = 0; ni < FN; ++ni) {
        const int gcol = bn0 + wn + ni * 16 + r16;
        const size_t o = (size_t)grow * N + gcol;
        const float v = acc[mi][ni][r];
        if constexpr (EPI == EPI_QKV) {
          const int seg = (bn0 + wn + ni * 16) >> 10;   // 0:q 1:k 2:v
          const float rv = (seg == 0) ? phi_fn(v) : (seg == 1 ? phi_fn(v) * mrow : v * mrow);
          outB[o] = f2bf(rv);
        } else if constexpr (EPI == EPI_WO) {
          outF[o] = v + res[o];
        } else if constexpr (EPI == EPI_W1) {
          const float t = v + bias[gcol];
          outB[o] = f2bf(0.5f * t * (1.f + erff(t * 0.70710678118654752f)));
        } else if constexpr (EPI == EPI_PART) {
          outF[o] = v;
        }
      }
    }
  }
}

// ---------------- split-K reduce for W2: out = p0+p1+bias+res ---------------
__global__ __launch_bounds__(256) void reduce_w2(
    const float* __restrict__ part, const float* __restrict__ res,
    const float* __restrict__ bias, float* __restrict__ out)
{
  const int row = blockIdx.x, tid = threadIdx.x;
  const size_t o = (size_t)row * 1024 + tid * 4;
  const float4 p0 = *(const float4*)&part[o];
  const float4 p1 = *(const float4*)&part[(size_t)2048 * 1024 + o];
  const float4 r = *(const float4*)&res[o];
  const float4 b = *(const float4*)&bias[tid * 4];
  float4 s;
  s.x = p0.x + p1.x + r.x + b.x;
  s.y = p0.y + p1.y + r.y + b.y;
  s.z = p0.z + p1.z + r.z + b.z;
  s.w = p0.w + p1.w + r.w + b.w;
  *(float4*)&out[o] = s;
}

// ---------------- attention phase 1: per-chunk K^T V and sum(k) -------------
// qkvB layout: [2048][3072] bf16, segments q|k|v of 1024 each.
__global__ __launch_bounds__(256) void chunk_sums(
    const unsigned short* __restrict__ qkvB, float* __restrict__ S,
    float* __restrict__ z)
{
  __shared__ float kS[64][68];
  __shared__ float vS[64][68];
  const int blk = blockIdx.x;
  const int bh = blk >> 4, c = blk & 15;
  const int b = bh >> 4, h = bh & 15;
  const int tid = threadIdx.x;
  const size_t base = ((size_t)(b * 1024 + c * 64)) * 3072 + h * 64;
  for (int it = 0; it < 2; ++it) {
    const int lin = it * 256 + tid;
    const int t = lin >> 3, f8 = (lin & 7) * 8;
    const us8 k8 = *(const us8*)&qkvB[base + 1024 + (size_t)t * 3072 + f8];
    const us8 v8 = *(const us8*)&qkvB[base + 2048 + (size_t)t * 3072 + f8];
#pragma unroll
    for (int j = 0; j < 8; ++j) {
      kS[t][f8 + j] = bf2f(k8[j]);
      vS[t][f8 + j] = bf2f(v8[j]);
    }
  }
  __syncthreads();
  const int fq = tid >> 2, dg = (tid & 3) * 16;
  float acc[16] = {};
  for (int t = 0; t < 64; ++t) {
    const float kk = kS[t][fq];
#pragma unroll
    for (int j = 0; j < 4; ++j) {
      const float4 vv = *(const float4*)&vS[t][dg + j * 4];
      acc[j*4+0] += kk * vv.x; acc[j*4+1] += kk * vv.y;
      acc[j*4+2] += kk * vv.z; acc[j*4+3] += kk * vv.w;
    }
  }
  float* Sp = S + ((size_t)bh * 16 + c) * 4096;
#pragma unroll
  for (int i = 0; i < 16; ++i) Sp[(size_t)fq * 64 + dg + i] = acc[i];
  if (tid < 64) {
    float s = 0.f;
    for (int t = 0; t < 64; ++t) s += kS[t][tid];
    z[((size_t)bh * 16 + c) * 64 + tid] = s;
  }
}

// ---------------- attention phase 2: parallel exclusive scan over chunks ----
// Each element's 16-chunk scan is independent: grid (32 bh x 8 sub).
__global__ __launch_bounds__(256) void scan_chunks(
    float* __restrict__ S, float* __restrict__ z)
{
  const int bh = blockIdx.x >> 3, sub = blockIdx.x & 7;
  const int tid = threadIdx.x;
  float* base = S + (size_t)bh * 16 * 4096 + sub * 512 + tid * 2;
  float r0 = 0.f, r1 = 0.f;
  for (int c = 0; c < 16; ++c) {
    float2* p = (float2*)(base + (size_t)c * 4096);
    const float2 cur = *p;
    *p = make_float2(r0, r1);
    r0 += cur.x; r1 += cur.y;
  }
  if (sub == 0 && tid < 64) {
    float zr = 0.f;
    for (int c = 0; c < 16; ++c) {
      float* zp = z + ((size_t)bh * 16 + c) * 64 + tid;
      const float cur = *zp; *zp = zr; zr += cur;
    }
  }
}

// ---------------- attention phase 3: per-chunk output -----------------------
__global__ __launch_bounds__(256) void attn_out_kernel(
    const unsigned short* __restrict__ qkvB, const float* __restrict__ Sp,
    const float* __restrict__ zp, unsigned short* __restrict__ attnB)
{
  __shared__ float qS[64][68];
  __shared__ float kvS[64][68];   // holds kf, then reused for v
  __shared__ float pS[64][68];
  __shared__ float zS[64];
  __shared__ float den[64];
  const int blk = blockIdx.x;
  const int bh = blk >> 4, c = blk & 15;
  const int b = bh >> 4, h = bh & 15;
  const int tid = threadIdx.x;
  const size_t base = ((size_t)(b * 1024 + c * 64)) * 3072 + h * 64;
  const size_t obase = ((size_t)(b * 1024 + c * 64)) * 1024 + h * 64;

  for (int it = 0; it < 2; ++it) {
    const int lin = it * 256 + tid;
    const int t = lin >> 3, f8 = (lin & 7) * 8;
    const us8 q8 = *(const us8*)&qkvB[base + (size_t)t * 3072 + f8];
    const us8 k8 = *(const us8*)&qkvB[base + 1024 + (size_t)t * 3072 + f8];
#pragma unroll
    for (int j = 0; j < 8; ++j) {
      qS[t][f8 + j] = bf2f(q8[j]);
      kvS[t][f8 + j] = bf2f(k8[j]);
    }
  }
  if (tid < 64) zS[tid] = zp[((size_t)bh * 16 + c) * 64 + tid];
  __syncthreads();

  const int tr = tid >> 4, tc = tid & 15;   // 4x4 register tile per thread
  float p[4][4] = {};
  for (int f = 0; f < 64; ++f) {
    float qv[4], kv[4];
#pragma unroll
    for (int i = 0; i < 4; ++i) { qv[i] = qS[tr*4+i][f]; kv[i] = kvS[tc*4+i][f]; }
#pragma unroll
    for (int i = 0; i < 4; ++i)
#pragma unroll
      for (int j = 0; j < 4; ++j) p[i][j] += qv[i] * kv[j];
  }
#pragma unroll
  for (int i = 0; i < 4; ++i)
#pragma unroll
    for (int j = 0; j < 4; ++j) {
      const int t = tr*4 + i, t2 = tc*4 + j;
      pS[t][t2] = (t2 <= t) ? p[i][j] : 0.f;   // causal mask
    }
  __syncthreads();
  for (int it = 0; it < 2; ++it) {           // overwrite kf-buffer with v
    const int lin = it * 256 + tid;
    const int t = lin >> 3, f8 = (lin & 7) * 8;
    const us8 v8 = *(const us8*)&qkvB[base + 2048 + (size_t)t * 3072 + f8];
#pragma unroll
    for (int j = 0; j < 8; ++j) kvS[t][f8 + j] = bf2f(v8[j]);
  }
  if (tid < 64) {
    const int t = tid;
    float d = 0.f;
    for (int f = 0; f < 64; ++f) d += qS[t][f] * zS[f];
    for (int t2 = 0; t2 <= t; ++t2) d += pS[t][t2];
    den[t] = d + 1e-6f;
  }
  __syncthreads();

  const float* SpB = Sp + ((size_t)bh * 16 + c) * 4096;  // [f][d]
  float o[4][4] = {};
  for (int f = 0; f < 64; ++f) {
    float qv[4];
#pragma unroll
    for (int i = 0; i < 4; ++i) qv[i] = qS[tr*4+i][f];
    const float4 sv = *(const float4*)&SpB[(size_t)f * 64 + tc * 4];
#pragma unroll
    for (int i = 0; i < 4; ++i) {
      o[i][0] += qv[i]*sv.x; o[i][1] += qv[i]*sv.y;
      o[i][2] += qv[i]*sv.z; o[i][3] += qv[i]*sv.w;
    }
  }
  for (int t2 = 0; t2 < 64; ++t2) {
    float pv[4];
#pragma unroll
    for (int i = 0; i < 4; ++i) pv[i] = pS[tr*4+i][t2];
    const float4 vv = *(const float4*)&kvS[t2][tc * 4];
#pragma unroll
    for (int i = 0; i < 4; ++i) {
      o[i][0] += pv[i]*vv.x; o[i][1] += pv[i]*vv.y;
      o[i][2] += pv[i]*vv.z; o[i][3] += pv[i]*vv.w;
    }
  }
#pragma unroll
  for (int i = 0; i < 4; ++i) {
    const int t = tr*4 + i;
    const float dinv = 1.f / den[t];
#pragma unroll
    for (int j = 0; j < 4; ++j)
      attnB[obase + (size_t)t * 1024 + tc * 4 + j] = f2bf(o[i][j] * dinv);
  }
}

// ---------------------------------------------------------------------------
extern "C" void kernel_launch(void* const* d_in, const int* in_sizes, int n_in,
                              void* d_out, int out_size, void* d_ws, size_t ws_size,
                              hipStream_t stream)
{
  (void)in_sizes; (void)n_in; (void)out_size; (void)ws_size;
  const float* x   = (const float*)d_in[0];
  const int*   msk = (const int*)d_in[1];
  const float* Wq  = (const float*)d_in[2];
  const float* Wk  = (const float*)d_in[3];
  const float* Wv  = (const float*)d_in[4];
  const float* Wo  = (const float*)d_in[5];
  const float* g1  = (const float*)d_in[6];
  const float* be1 = (const float*)d_in[7];
  const float* g2  = (const float*)d_in[8];
  const float* be2 = (const float*)d_in[9];
  const float* W1  = (const float*)d_in[10];
  const float* b1  = (const float*)d_in[11];
  const float* W2  = (const float*)d_in[12];
  const float* b2  = (const float*)d_in[13];
  float* out = (float*)d_out;

  char* ws = (char*)d_ws;
  const size_t MB = 1024 * 1024;
  unsigned short* WqkvT = (unsigned short*)(ws + 0 * MB);   // [3072][1024] bf16
  unsigned short* WoT   = (unsigned short*)(ws + 6 * MB);   // [1024][1024]
  unsigned short* W1T   = (unsigned short*)(ws + 8 * MB);   // [4096][1024]
  unsigned short* W2T   = (unsigned short*)(ws + 16 * MB);  // [1024][4096]
  unsigned short* hB    = (unsigned short*)(ws + 24 * MB);  // LN1 out bf16
  unsigned short* qkvB  = (unsigned short*)(ws + 28 * MB);  // [2048][3072] bf16
  float* Ssum = (float*)(ws + 40 * MB);                     // [32][16][64][64]
  float* zsum = (float*)(ws + 48 * MB);                     // [32][16][64]
  unsigned short* attnB = (unsigned short*)(ws + 49 * MB);  // [2048][1024] bf16
  float* x2   = (float*)(ws + 53 * MB);                     // [2048][1024] fp32
  unsigned short* h2B = (unsigned short*)(ws + 61 * MB);    // LN2 out bf16
  unsigned short* ffB = (unsigned short*)(ws + 65 * MB);    // [2048][4096] bf16
  float* part = (float*)(ws + 28 * MB);  // [2][2048][1024] fp32, reuses qkv/Ssum (dead by W2)

  const dim3 B256(256);
  cvt_all<<<3072, B256, 0, stream>>>(Wq, Wk, Wv, Wo, W1, W2, WqkvT, WoT, W1T, W2T);
  ln_to_bf16<<<2048, B256, 0, stream>>>(x, g1, be1, hB);

  gemm_bf16<128, 128, EPI_QKV><<<dim3(24, 16), B256, 0, stream>>>(
      hB, WqkvT, nullptr, nullptr, msk, nullptr, qkvB, 2048, 3072, 1024, 1024, 1024);

  chunk_sums<<<512, B256, 0, stream>>>(qkvB, Ssum, zsum);
  scan_chunks<<<256, B256, 0, stream>>>(Ssum, zsum);
  attn_out_kernel<<<512, B256, 0, stream>>>(qkvB, Ssum, zsum, attnB);

  gemm_bf16<128, 64, EPI_WO><<<dim3(16, 16), B256, 0, stream>>>(
      attnB, WoT, nullptr, x, nullptr, x2, nullptr, 2048, 1024, 1024, 1024, 1024);

  ln_to_bf16<<<2048, B256, 0, stream>>>(x2, g2, be2, h2B);

  gemm_bf16<128, 128, EPI_W1><<<dim3(32, 16), B256, 0, stream>>>(
      h2B, W1T, b1, nullptr, nullptr, nullptr, ffB, 2048, 4096, 1024, 1024, 1024);

  // W2 split-K=2: partials then reduce (+bias +residual)
  gemm_bf16<128, 64, EPI_PART><<<dim3(16, 16, 2), B256, 0, stream>>>(
      ffB, W2T, nullptr, nullptr, nullptr, part, nullptr, 2048, 1024, 2048, 4096, 4096);
  reduce_w2<<<2048, B256, 0, stream>>>(part, x2, b2, out);
}

// Round 6
// 242.657 us; speedup vs baseline: 1.6559x; 1.0839x over previous
//
#include <hip/hip_runtime.h>
#include <math.h>

// ---------------------------------------------------------------------------
// LinearBlock: LN -> fused QKV GEMM -> causal linear attention (elu+1)
//              -> Wo+res -> LN -> GELU MLP + res.
// B=2 T=1024 D=1024 H=16 DH=64 FF=4096.
// GEMMs: bf16 MFMA, BK=64, dbuf gload_lds with COUNTED vmcnt pipeline (T3+T4:
// raw s_barrier, never drain vmcnt to 0 mid-loop), setprio on MFMA cluster
// (T5), XOR-swizzled LDS (pre-swizzled global src, rule #21), XCD-chunked
// remap (T1).  Attn: fp32 chunked scan.
// ---------------------------------------------------------------------------

typedef __attribute__((ext_vector_type(8))) __bf16 bf16x8;
typedef __attribute__((ext_vector_type(8))) unsigned short us8;
typedef __attribute__((ext_vector_type(4))) float f32x4;

__device__ __forceinline__ unsigned short f2bf(float f) {
  unsigned int u = __builtin_bit_cast(unsigned int, f);
  unsigned int r = (u + 0x7fffu + ((u >> 16) & 1u)) >> 16;  // RNE
  return (unsigned short)r;
}
__device__ __forceinline__ float bf2f(unsigned short u) {
  return __builtin_bit_cast(float, ((unsigned int)u) << 16);
}
__device__ __forceinline__ float phi_fn(float x) {  // elu(x)+1
  return x > 0.f ? x + 1.f : __expf(x);
}

// async global->LDS, 16B/lane; LDS dest = wave-uniform base + lane*16 (linear)
__device__ __forceinline__ void gload16(const unsigned short* g, unsigned short* l) {
  __builtin_amdgcn_global_load_lds(
      (const __attribute__((address_space(1))) unsigned int*)(const void*)g,
      (__attribute__((address_space(3))) unsigned int*)(void*)l, 16, 0, 0);
}

// ---------------- LayerNorm row (D=1024) fp32 in -> bf16 out ----------------
__device__ __forceinline__ void ln_row(
    const float* __restrict__ x, const float* __restrict__ g,
    const float* __restrict__ b, unsigned short* __restrict__ out,
    int row, int tid)
{
  const float4 xv = *(const float4*)&x[(size_t)row * 1024 + tid * 4];
  float xa[4] = {xv.x, xv.y, xv.z, xv.w};
  float s = xa[0] + xa[1] + xa[2] + xa[3];
  float sq = xa[0]*xa[0] + xa[1]*xa[1] + xa[2]*xa[2] + xa[3]*xa[3];
  for (int off = 32; off > 0; off >>= 1) {
    s += __shfl_down(s, off);
    sq += __shfl_down(sq, off);
  }
  __shared__ float red[8];
  if ((tid & 63) == 0) { red[tid >> 6] = s; red[4 + (tid >> 6)] = sq; }
  __syncthreads();
  const float ts = red[0] + red[1] + red[2] + red[3];
  const float tq = red[4] + red[5] + red[6] + red[7];
  const float mean = ts * (1.f / 1024.f);
  const float var = tq * (1.f / 1024.f) - mean * mean;
  const float inv = rsqrtf(var + 1e-5f);
  unsigned short o[4];
#pragma unroll
  for (int j = 0; j < 4; ++j) {
    const int col = tid * 4 + j;
    o[j] = f2bf((xa[j] - mean) * inv * g[col] + b[col]);
  }
  unsigned int p0 = (unsigned)o[0] | ((unsigned)o[1] << 16);
  unsigned int p1 = (unsigned)o[2] | ((unsigned)o[3] << 16);
  *(uint2*)(out + (size_t)row * 1024 + tid * 4) = make_uint2(p0, p1);
}

__global__ __launch_bounds__(256) void ln_to_bf16(
    const float* __restrict__ x, const float* __restrict__ g,
    const float* __restrict__ b, unsigned short* __restrict__ out)
{
  ln_row(x, g, b, out, blockIdx.x, threadIdx.x);
}

// ---------------- weight convert + transpose + LN1 (one dispatch) -----------
__device__ __forceinline__ void cvt_tile(
    const float* __restrict__ W, unsigned short* __restrict__ WT,
    int K, int N, int tk, int tn, int tid)
{
  __shared__ unsigned short tile[64][72];
  const int n0 = tn * 64, k0 = tk * 64;
  for (int it = 0; it < 16; ++it) {
    const int lin = it * 256 + tid;
    const int i = lin >> 6, j = lin & 63;            // i: k, j: n
    tile[j][i] = f2bf(W[(size_t)(k0 + i) * N + n0 + j]);
  }
  __syncthreads();
  for (int it = 0; it < 16; ++it) {
    const int lin = it * 256 + tid;
    const int j = lin >> 6, i = lin & 63;
    WT[(size_t)(n0 + j) * K + k0 + i] = tile[j][i];
  }
}

__global__ __launch_bounds__(256) void cvt_all(
    const float* __restrict__ Wq, const float* __restrict__ Wk,
    const float* __restrict__ Wv, const float* __restrict__ Wo,
    const float* __restrict__ W1, const float* __restrict__ W2,
    unsigned short* __restrict__ WqkvT, unsigned short* __restrict__ WoT,
    unsigned short* __restrict__ W1T, unsigned short* __restrict__ W2T,
    const float* __restrict__ x, const float* __restrict__ g1,
    const float* __restrict__ be1, unsigned short* __restrict__ hB)
{
  const int bid = blockIdx.x, tid = threadIdx.x;
  if (bid < 768) {                    // Wq,Wk,Wv -> stacked [3072][1024]
    const int wsel = bid >> 8, local = bid & 255;
    const float* W = wsel == 0 ? Wq : (wsel == 1 ? Wk : Wv);
    cvt_tile(W, WqkvT + (size_t)wsel * 1024 * 1024, 1024, 1024, local >> 4, local & 15, tid);
  } else if (bid < 1024) {
    const int local = bid - 768;
    cvt_tile(Wo, WoT, 1024, 1024, local >> 4, local & 15, tid);
  } else if (bid < 2048) {            // W1: [1024][4096] -> [4096][1024]
    const int local = bid - 1024;
    cvt_tile(W1, W1T, 1024, 4096, local >> 6, local & 63, tid);
  } else if (bid < 3072) {            // W2: [4096][1024] -> [1024][4096]
    const int local = bid - 2048;
    cvt_tile(W2, W2T, 4096, 1024, local >> 4, local & 15, tid);
  } else {                            // LN1 rows (independent of weights)
    ln_row(x, g1, be1, hB, bid - 3072, tid);
  }
}

// ---------------- bf16 MFMA GEMM: BK=64, dbuf, counted-vmcnt pipeline -------
enum { EPI_QKV = 0, EPI_WO = 1, EPI_W1 = 2, EPI_PART = 3 };

template <int BM, int BN, int EPI>
__global__ __launch_bounds__(256) void gemm_bf16(
    const unsigned short* __restrict__ A,   // [M][lda] bf16
    const unsigned short* __restrict__ BT,  // [N][ldb] bf16 (pre-transposed)
    const float* __restrict__ bias, const float* __restrict__ res,
    const int* __restrict__ mask,
    float* __restrict__ outF, unsigned short* __restrict__ outB,
    int M, int N, int K, int lda, int ldb)
{
  constexpr int FM = BM / 32, FN = BN / 32;   // 16x16 frags per wave (per k-half)
  constexpr int IA = BM / 32, IB = BN / 32;   // 8-row gload issues per wave
  constexpr int LPS = IA + IB;                // vmem insts per stage per thread
  static_assert(LPS == 8 || LPS == 6, "vmcnt literal");
  __shared__ __align__(16) unsigned short lA[2][BM * 64];  // [row][64] linear
  __shared__ __align__(16) unsigned short lB[2][BN * 64];
  const int tid = threadIdx.x;

  // XCD-chunked remap: 2(bm)x4(bn) super-tiles, one per 8-slot XCD chunk.
  int bn_i, bm_i;
  {
    const int gx = gridDim.x, gy = gridDim.y;
    const int i = blockIdx.x + blockIdx.y * gx;
    const int nwg = gx * gy;
    if (((nwg & 63) == 0) && ((gx & 3) == 0) && ((gy & 1) == 0)) {
      const int k8 = i & 7, j = i >> 3;
      const int G = k8 + (j >> 3) * 8;   // super-group id (G%8 == xcd)
      const int p = j & 7;
      const int sgx = gx >> 2;
      bm_i = (G / sgx) * 2 + (p >> 2);
      bn_i = (G % sgx) * 4 + (p & 3);
    } else { bn_i = blockIdx.x; bm_i = blockIdx.y; }
  }
  const int bn0 = bn_i * BN, bm0 = bm_i * BM;
  const int kz = blockIdx.z;                  // split-K slice
  A  += (size_t)kz * K;                       // col shift (lda covers it)
  BT += (size_t)kz * K;
  if constexpr (EPI == EPI_PART) outF += (size_t)kz * M * N;

  const int w = tid >> 6, l = tid & 63;
  const int wm = (w >> 1) * (BM / 2), wn = (w & 1) * (BN / 2);
  const int r16 = l & 15, g = l >> 4;
  // staging: 8 rows/issue; global col-group pre-XOR'd so linear LDS holds
  // swizzled layout (slot s of row r = col-group s^(r&7))
  const int srow8 = l >> 3;                        // 0..7
  const int scolg = ((l & 7) ^ srow8) * 8;         // element col in tile
  f32x4 acc[FM][FN] = {};

  const unsigned short* Ab = A + (size_t)bm0 * lda;
  const unsigned short* Bb = BT + (size_t)bn0 * ldb;
  const int nsteps = K >> 6;

  auto stage = [&](int s, int buf) {
    const int kc = s << 6;
#pragma unroll
    for (int ii = 0; ii < IA; ++ii) {
      const int r0 = (w * IA + ii) * 8;
      gload16(&Ab[(size_t)(r0 + srow8) * lda + kc + scolg], &lA[buf][r0 * 64]);
    }
#pragma unroll
    for (int ii = 0; ii < IB; ++ii) {
      const int r0 = (w * IB + ii) * 8;
      gload16(&Bb[(size_t)(r0 + srow8) * ldb + kc + scolg], &lB[buf][r0 * 64]);
    }
  };

  stage(0, 0);
  stage(1, 1);
  int cur = 0;
  for (int s = 0; s < nsteps; ++s) {
    // T4: wait only for stage(s); stage(s+1) loads stay in flight.
    if (s + 1 < nsteps) {
      if constexpr (LPS == 8) asm volatile("s_waitcnt vmcnt(8)" ::: "memory");
      else                    asm volatile("s_waitcnt vmcnt(6)" ::: "memory");
    } else {
      asm volatile("s_waitcnt vmcnt(0)" ::: "memory");
    }
    __builtin_amdgcn_s_barrier();      // buf[cur] fully staged for all waves

    bf16x8 av[2][FM], bv[2][FN];
#pragma unroll
    for (int h = 0; h < 2; ++h) {
#pragma unroll
      for (int mi = 0; mi < FM; ++mi) {
        const int row = wm + mi * 16 + r16;
        const int grp = (h * 4 + g) ^ (r16 & 7);
        av[h][mi] = __builtin_bit_cast(bf16x8, *(const us8*)&lA[cur][row * 64 + grp * 8]);
      }
#pragma unroll
      for (int ni = 0; ni < FN; ++ni) {
        const int row = wn + ni * 16 + r16;
        const int grp = (h * 4 + g) ^ (r16 & 7);
        bv[h][ni] = __builtin_bit_cast(bf16x8, *(const us8*)&lB[cur][row * 64 + grp * 8]);
      }
    }
    asm volatile("s_waitcnt lgkmcnt(0)" ::: "memory");  // my ds_reads landed
    __builtin_amdgcn_sched_barrier(0);                  // rule #18
    __builtin_amdgcn_s_barrier();      // all waves done reading buf[cur]
    if (s + 2 < nsteps) stage(s + 2, cur);              // async refill

    __builtin_amdgcn_s_setprio(1);
#pragma unroll
    for (int h = 0; h < 2; ++h)
#pragma unroll
      for (int mi = 0; mi < FM; ++mi)
#pragma unroll
        for (int ni = 0; ni < FN; ++ni)
          acc[mi][ni] = __builtin_amdgcn_mfma_f32_16x16x32_bf16(av[h][mi], bv[h][ni], acc[mi][ni], 0, 0, 0);
    __builtin_amdgcn_s_setprio(0);
    cur ^= 1;
  }

#pragma unroll
  for (int mi = 0; mi < FM; ++mi) {
#pragma unroll
    for (int r = 0; r < 4; ++r) {
      const int grow = bm0 + wm + mi * 16 + g * 4 + r;  // C/D: col=lane&15, row=(lane>>4)*4+reg
      float mrow = 0.f;
      if constexpr (EPI == EPI_QKV) mrow = (float)mask[grow];
#pragma unroll
      for (int ni = 0; ni < FN; ++ni) {
        const int gcol = bn0 + wn + ni * 16 + r16;
        const size_t o = (size_t)grow * N + gcol;
        const float v = acc[mi][ni][r];
        if constexpr (EPI == EPI_QKV) {
          const int seg = (bn0 + wn + ni * 16) >> 10;   // 0:q 1:k 2:v
          const float rv = (seg == 0) ? phi_fn(v) : (seg == 1 ? phi_fn(v) * mrow : v * mrow);
          outB[o] = f2bf(rv);
        } else if constexpr (EPI == EPI_WO) {
          outF[o] = v + res[o];
        } else if constexpr (EPI == EPI_W1) {
          const float t = v + bias[gcol];
          outB[o] = f2bf(0.5f * t * (1.f + erff(t * 0.70710678118654752f)));
        } else if constexpr (EPI == EPI_PART) {
          outF[o] = v;
        }
      }
    }
  }
}

// ---------------- split-K reduce for W2: out = p0+p1+bias+res ---------------
__global__ __launch_bounds__(256) void reduce_w2(
    const float* __restrict__ part, const float* __restrict__ res,
    const float* __restrict__ bias, float* __restrict__ out)
{
  const int row = blockIdx.x, tid = threadIdx.x;
  const size_t o = (size_t)row * 1024 + tid * 4;
  const float4 p0 = *(const float4*)&part[o];
  const float4 p1 = *(const float4*)&part[(size_t)2048 * 1024 + o];
  const float4 r = *(const float4*)&res[o];
  const float4 b = *(const float4*)&bias[tid * 4];
  float4 s;
  s.x = p0.x + p1.x + r.x + b.x;
  s.y = p0.y + p1.y + r.y + b.y;
  s.z = p0.z + p1.z + r.z + b.z;
  s.w = p0.w + p1.w + r.w + b.w;
  *(float4*)&out[o] = s;
}

// ---------------- attention phase 1: per-chunk K^T V and sum(k) -------------
// qkvB layout: [2048][3072] bf16, segments q|k|v of 1024 each.
__global__ __launch_bounds__(256) void chunk_sums(
    const unsigned short* __restrict__ qkvB, float* __restrict__ S,
    float* __restrict__ z)
{
  __shared__ float kS[64][68];
  __shared__ float vS[64][68];
  const int blk = blockIdx.x;
  const int bh = blk >> 4, c = blk & 15;
  const int b = bh >> 4, h = bh & 15;
  const int tid = threadIdx.x;
  const size_t base = ((size_t)(b * 1024 + c * 64)) * 3072 + h * 64;
  for (int it = 0; it < 2; ++it) {
    const int lin = it * 256 + tid;
    const int t = lin >> 3, f8 = (lin & 7) * 8;
    const us8 k8 = *(const us8*)&qkvB[base + 1024 + (size_t)t * 3072 + f8];
    const us8 v8 = *(const us8*)&qkvB[base + 2048 + (size_t)t * 3072 + f8];
#pragma unroll
    for (int j = 0; j < 8; ++j) {
      kS[t][f8 + j] = bf2f(k8[j]);
      vS[t][f8 + j] = bf2f(v8[j]);
    }
  }
  __syncthreads();
  const int fq = tid >> 2, dg = (tid & 3) * 16;
  float acc[16] = {};
  for (int t = 0; t < 64; ++t) {
    const float kk = kS[t][fq];
#pragma unroll
    for (int j = 0; j < 4; ++j) {
      const float4 vv = *(const float4*)&vS[t][dg + j * 4];
      acc[j*4+0] += kk * vv.x; acc[j*4+1] += kk * vv.y;
      acc[j*4+2] += kk * vv.z; acc[j*4+3] += kk * vv.w;
    }
  }
  float* Sp = S + ((size_t)bh * 16 + c) * 4096;
#pragma unroll
  for (int i = 0; i < 16; ++i) Sp[(size_t)fq * 64 + dg + i] = acc[i];
  if (tid < 64) {
    float s = 0.f;
    for (int t = 0; t < 64; ++t) s += kS[t][tid];
    z[((size_t)bh * 16 + c) * 64 + tid] = s;
  }
}

// ---------------- attention phase 2: parallel exclusive scan over chunks ----
// Preload all 16 chunks (independent loads in flight), scan in regs, store.
__global__ __launch_bounds__(256) void scan_chunks(
    float* __restrict__ S, float* __restrict__ z)
{
  const int bh = blockIdx.x >> 3, sub = blockIdx.x & 7;
  const int tid = threadIdx.x;
  float* base = S + (size_t)bh * 16 * 4096 + sub * 512 + tid * 2;
  float2 v[16];
#pragma unroll
  for (int c = 0; c < 16; ++c) v[c] = *(float2*)(base + (size_t)c * 4096);
  float r0 = 0.f, r1 = 0.f;
#pragma unroll
  for (int c = 0; c < 16; ++c) {
    const float2 cv = v[c];
    *(float2*)(base + (size_t)c * 4096) = make_float2(r0, r1);
    r0 += cv.x; r1 += cv.y;
  }
  if (sub == 0 && tid < 64) {
    float* zp = z + (size_t)bh * 16 * 64 + tid;
    float zv[16];
#pragma unroll
    for (int c = 0; c < 16; ++c) zv[c] = zp[c * 64];
    float zr = 0.f;
#pragma unroll
    for (int c = 0; c < 16; ++c) { zp[c * 64] = zr; zr += zv[c]; }
  }
}

// ---------------- attention phase 3: per-chunk output -----------------------
__global__ __launch_bounds__(256) void attn_out_kernel(
    const unsigned short* __restrict__ qkvB, const float* __restrict__ Sp,
    const float* __restrict__ zp, unsigned short* __restrict__ attnB)
{
  __shared__ float qS[64][68];
  __shared__ float kvS[64][68];   // holds kf, then reused for v
  __shared__ float pS[64][68];
  __shared__ float zS[64];
  __shared__ float den[64];
  const int blk = blockIdx.x;
  const int bh = blk >> 4, c = blk & 15;
  const int b = bh >> 4, h = bh & 15;
  const int tid = threadIdx.x;
  const size_t base = ((size_t)(b * 1024 + c * 64)) * 3072 + h * 64;
  const size_t obase = ((size_t)(b * 1024 + c * 64)) * 1024 + h * 64;

  for (int it = 0; it < 2; ++it) {
    const int lin = it * 256 + tid;
    const int t = lin >> 3, f8 = (lin & 7) * 8;
    const us8 q8 = *(const us8*)&qkvB[base + (size_t)t * 3072 + f8];
    const us8 k8 = *(const us8*)&qkvB[base + 1024 + (size_t)t * 3072 + f8];
#pragma unroll
    for (int j = 0; j < 8; ++j) {
      qS[t][f8 + j] = bf2f(q8[j]);
      kvS[t][f8 + j] = bf2f(k8[j]);
    }
  }
  if (tid < 64) zS[tid] = zp[((size_t)bh * 16 + c) * 64 + tid];
  __syncthreads();

  const int tr = tid >> 4, tc = tid & 15;   // 4x4 register tile per thread
  float p[4][4] = {};
  for (int f = 0; f < 64; ++f) {
    float qv[4], kv[4];
#pragma unroll
    for (int i = 0; i < 4; ++i) { qv[i] = qS[tr*4+i][f]; kv[i] = kvS[tc*4+i][f]; }
#pragma unroll
    for (int i = 0; i < 4; ++i)
#pragma unroll
      for (int j = 0; j < 4; ++j) p[i][j] += qv[i] * kv[j];
  }
#pragma unroll
  for (int i = 0; i < 4; ++i)
#pragma unroll
    for (int j = 0; j < 4; ++j) {
      const int t = tr*4 + i, t2 = tc*4 + j;
      pS[t][t2] = (t2 <= t) ? p[i][j] : 0.f;   // causal mask
    }
  __syncthreads();
  for (int it = 0; it < 2; ++it) {           // overwrite kf-buffer with v
    const int lin = it * 256 + tid;
    const int t = lin >> 3, f8 = (lin & 7) * 8;
    const us8 v8 = *(const us8*)&qkvB[base + 2048 + (size_t)t * 3072 + f8];
#pragma unroll
    for (int j = 0; j < 8; ++j) kvS[t][f8 + j] = bf2f(v8[j]);
  }
  if (tid < 64) {
    const int t = tid;
    float d = 0.f;
    for (int f = 0; f < 64; ++f) d += qS[t][f] * zS[f];
    for (int t2 = 0; t2 <= t; ++t2) d += pS[t][t2];
    den[t] = d + 1e-6f;
  }
  __syncthreads();

  const float* SpB = Sp + ((size_t)bh * 16 + c) * 4096;  // [f][d]
  float o[4][4] = {};
  for (int f = 0; f < 64; ++f) {
    float qv[4];
#pragma unroll
    for (int i = 0; i < 4; ++i) qv[i] = qS[tr*4+i][f];
    const float4 sv = *(const float4*)&SpB[(size_t)f * 64 + tc * 4];
#pragma unroll
    for (int i = 0; i < 4; ++i) {
      o[i][0] += qv[i]*sv.x; o[i][1] += qv[i]*sv.y;
      o[i][2] += qv[i]*sv.z; o[i][3] += qv[i]*sv.w;
    }
  }
  for (int t2 = 0; t2 < 64; ++t2) {
    float pv[4];
#pragma unroll
    for (int i = 0; i < 4; ++i) pv[i] = pS[tr*4+i][t2];
    const float4 vv = *(const float4*)&kvS[t2][tc * 4];
#pragma unroll
    for (int i = 0; i < 4; ++i) {
      o[i][0] += pv[i]*vv.x; o[i][1] += pv[i]*vv.y;
      o[i][2] += pv[i]*vv.z; o[i][3] += pv[i]*vv.w;
    }
  }
#pragma unroll
  for (int i = 0; i < 4; ++i) {
    const int t = tr*4 + i;
    const float dinv = 1.f / den[t];
#pragma unroll
    for (int j = 0; j < 4; ++j)
      attnB[obase + (size_t)t * 1024 + tc * 4 + j] = f2bf(o[i][j] * dinv);
  }
}

// ---------------------------------------------------------------------------
extern "C" void kernel_launch(void* const* d_in, const int* in_sizes, int n_in,
                              void* d_out, int out_size, void* d_ws, size_t ws_size,
                              hipStream_t stream)
{
  (void)in_sizes; (void)n_in; (void)out_size; (void)ws_size;
  const float* x   = (const float*)d_in[0];
  const int*   msk = (const int*)d_in[1];
  const float* Wq  = (const float*)d_in[2];
  const float* Wk  = (const float*)d_in[3];
  const float* Wv  = (const float*)d_in[4];
  const float* Wo  = (const float*)d_in[5];
  const float* g1  = (const float*)d_in[6];
  const float* be1 = (const float*)d_in[7];
  const float* g2  = (const float*)d_in[8];
  const float* be2 = (const float*)d_in[9];
  const float* W1  = (const float*)d_in[10];
  const float* b1  = (const float*)d_in[11];
  const float* W2  = (const float*)d_in[12];
  const float* b2  = (const float*)d_in[13];
  float* out = (float*)d_out;

  char* ws = (char*)d_ws;
  const size_t MB = 1024 * 1024;
  unsigned short* WqkvT = (unsigned short*)(ws + 0 * MB);   // [3072][1024] bf16
  unsigned short* WoT   = (unsigned short*)(ws + 6 * MB);   // [1024][1024]
  unsigned short* W1T   = (unsigned short*)(ws + 8 * MB);   // [4096][1024]
  unsigned short* W2T   = (unsigned short*)(ws + 16 * MB);  // [1024][4096]
  unsigned short* hB    = (unsigned short*)(ws + 24 * MB);  // LN1 out bf16
  unsigned short* qkvB  = (unsigned short*)(ws + 28 * MB);  // [2048][3072] bf16
  float* Ssum = (float*)(ws + 40 * MB);                     // [32][16][64][64]
  float* zsum = (float*)(ws + 48 * MB);                     // [32][16][64]
  unsigned short* attnB = (unsigned short*)(ws + 49 * MB);  // [2048][1024] bf16
  float* x2   = (float*)(ws + 53 * MB);                     // [2048][1024] fp32
  unsigned short* h2B = (unsigned short*)(ws + 61 * MB);    // LN2 out bf16
  unsigned short* ffB = (unsigned short*)(ws + 65 * MB);    // [2048][4096] bf16
  float* part = (float*)(ws + 28 * MB);  // [2][2048][1024] fp32, reuses qkv/Ssum (dead by W2)

  const dim3 B256(256);
  cvt_all<<<5120, B256, 0, stream>>>(Wq, Wk, Wv, Wo, W1, W2, WqkvT, WoT, W1T, W2T,
                                     x, g1, be1, hB);

  gemm_bf16<128, 128, EPI_QKV><<<dim3(24, 16), B256, 0, stream>>>(
      hB, WqkvT, nullptr, nullptr, msk, nullptr, qkvB, 2048, 3072, 1024, 1024, 1024);

  chunk_sums<<<512, B256, 0, stream>>>(qkvB, Ssum, zsum);
  scan_chunks<<<256, B256, 0, stream>>>(Ssum, zsum);
  attn_out_kernel<<<512, B256, 0, stream>>>(qkvB, Ssum, zsum, attnB);

  gemm_bf16<128, 64, EPI_WO><<<dim3(16, 16), B256, 0, stream>>>(
      attnB, WoT, nullptr, x, nullptr, x2, nullptr, 2048, 1024, 1024, 1024, 1024);

  ln_to_bf16<<<2048, B256, 0, stream>>>(x2, g2, be2, h2B);

  gemm_bf16<128, 128, EPI_W1><<<dim3(32, 16), B256, 0, stream>>>(
      h2B, W1T, b1, nullptr, nullptr, nullptr, ffB, 2048, 4096, 1024, 1024, 1024);

  // W2 split-K=2: partials then reduce (+bias +residual)
  gemm_bf16<128, 64, EPI_PART><<<dim3(16, 16, 2), B256, 0, stream>>>(
      ffB, W2T, nullptr, nullptr, nullptr, part, nullptr, 2048, 1024, 2048, 4096, 4096);
  reduce_w2<<<2048, B256, 0, stream>>>(part, x2, b2, out);
}